// Round 12
// baseline (370.877 us; speedup 1.0000x reference)
//
#include <hip/hip_runtime.h>
#include <hip/hip_bf16.h>
#include <stdint.h>
#include <stddef.h>

// ---------------------------------------------------------------------------
// NonLocalBlock2D: B=8, C=256, H=W=64 (N=4096), CI=128
// out = x + Wout * softmax( (theta(x)^T phi(x)) * sqrt(CI) ) * g(x)
// Split-fp32 (bf16 hi+lo, 3-MFMA) upstream of softmax; plain bf16 after.
// theta pre-scaled by sqrt(128)/ln2 -> softmax in exp2 domain.
// k_proj3: three projections fused (x staged once) + w_out pre-convert.
// k_attn_sp: BK=64 — 512 blocks x 256 thr (2 blocks/CU, 8 waves/CU),
// 4 waves x 32 q, KV-split x2; K double-buffered LDS + reg prefetch,
// 1 barrier/iter (32 iters); V fragment-major from L2, issued after QK^T.
// k_out: combine of KV-split partials fused into the output GEMM; uses
// pre-converted bf16 w_out when workspace permits.
// ---------------------------------------------------------------------------

typedef __bf16 bf16;
typedef __attribute__((ext_vector_type(8))) __bf16 bf16x8;
typedef __attribute__((ext_vector_type(4))) __bf16 bf16x4;
typedef __attribute__((ext_vector_type(4))) float  f32x4;
typedef __attribute__((ext_vector_type(4))) int    i32x4;

#define MFMA16(a, b, c) __builtin_amdgcn_mfma_f32_16x16x32_bf16((a), (b), (c), 0, 0, 0)

constexpr int NB  = 8;
constexpr int NC  = 256;
constexpr int NN  = 4096;
constexpr int NCI = 128;
constexpr size_t NEL = (size_t)NB * NN * NCI;
constexpr int PBATCH = NN * NCI;       // elems per batch

// sqrt(128) / ln(2): folded into theta so logits are in log2 units.
#define QSCALE (11.313708498984761f * 1.4426950408889634f)

// V fragment layout (16x16x32 MFMA B-operand):
//  Vf[b][m>>6][j=d>>4][tt=(m&63)>>5][lane][8], lane=((m>>3)&3)*16+(d&15), e=m&7

// ---------------------------------------------------------------------------
// Kernel 1: fused projections. Block (nt, b) computes theta/phi/g for a
// 64-n x 128-i tile. x-tile staged (and fp32-split) ONCE per c0 chunk;
// W staged sequentially per projection in a reused LDS buffer.
// theta -> qh/ql (*QSCALE), phi -> kh/kl, g -> fragment-major vv.
// If wob != null, also pre-converts w_out fp32->bf16 (64 elems/block).
// ---------------------------------------------------------------------------
__global__ __launch_bounds__(256) void k_proj3(
    const float* __restrict__ x,
    const float* __restrict__ wt, const float* __restrict__ bt,
    const float* __restrict__ wp, const float* __restrict__ bp,
    const float* __restrict__ wg, const float* __restrict__ bg,
    const float* __restrict__ wo, bf16* __restrict__ wob,
    bf16* __restrict__ qh, bf16* __restrict__ ql,
    bf16* __restrict__ kh, bf16* __restrict__ kl,
    bf16* __restrict__ vv)
{
    const int nt  = blockIdx.x;      // 0..63
    const int b   = blockIdx.y;      // 0..7
    const int tid = threadIdx.x;
    const int wv  = tid >> 6;
    const int ln  = tid & 63;
    const int lg  = ln >> 4;
    const int lq  = ln & 15;

    // side job: pre-convert w_out (256x128 fp32 -> bf16), 64 elems per block
    if (wob != nullptr && tid < 16) {
        int idx = (b * 64 + nt) * 64 + tid * 4;
        f32x4 w4 = *(const f32x4*)(wo + idx);
        bf16x4 o4;
#pragma unroll
        for (int e = 0; e < 4; ++e) o4[e] = (bf16)w4[e];
        *(bf16x4*)(wob + idx) = o4;
    }

    __shared__ char lds[49152];
    char* Ah = lds;            // [64 n][64 c] bf16 hi, swizzled (8 KB)
    char* Al = lds + 8192;     // lo
    char* Wh = lds + 16384;    // [128 i][64 c] bf16 hi, swizzled (16 KB)
    char* Wl = lds + 32768;    // lo

    f32x4 acc[3][8];
#pragma unroll
    for (int pj = 0; pj < 3; ++pj)
#pragma unroll
        for (int j = 0; j < 8; ++j) acc[pj][j] = f32x4{0.f, 0.f, 0.f, 0.f};

    const int n0 = nt * 64;

    for (int c0 = 0; c0 < NC; c0 += 64) {
        __syncthreads();
        // ---- stage x chunk once: x[b, c0+cc, n0+nn] -> Ah/Al[nn][cc]
#pragma unroll
        for (int p = 0; p < 4; ++p) {
            int cc = p * 16 + (tid >> 4);
            int nn = (tid & 15) * 4;
            f32x4 xv = *(const f32x4*)(x + ((size_t)b * NC + (c0 + cc)) * NN + n0 + nn);
#pragma unroll
            for (int e = 0; e < 4; ++e) {
                float f = xv[e];
                bf16 hh = (bf16)f;
                int row = nn + e;
                int off = (row * 128 + cc * 2) ^ ((row & 7) << 4);
                *(bf16*)(Ah + off) = hh;
                *(bf16*)(Al + off) = (bf16)(f - (float)hh);
            }
        }

        // ---- three projections, sequential W staging
#pragma unroll
        for (int pj = 0; pj < 3; ++pj) {
            const float* W = (pj == 0) ? wt : (pj == 1) ? wp : wg;
            const bool split = (pj != 2);
            if (pj != 0) __syncthreads();   // done reading previous W
#pragma unroll
            for (int p = 0; p < 8; ++p) {
                int i  = p * 16 + (tid >> 4);
                int c4 = (tid & 15) * 4;
                f32x4 w4 = *(const f32x4*)(W + (size_t)i * NC + c0 + c4);
                bf16x4 hv, lv;
#pragma unroll
                for (int e = 0; e < 4; ++e) {
                    bf16 hh = (bf16)w4[e];
                    hv[e] = hh;
                    lv[e] = (bf16)(w4[e] - (float)hh);
                }
                int off = (i * 128 + c4 * 2) ^ ((i & 7) << 4);
                *(bf16x4*)(Wh + off) = hv;
                if (split) *(bf16x4*)(Wl + off) = lv;
            }
            __syncthreads();
#pragma unroll
            for (int kk = 0; kk < 2; ++kk) {
                int row  = wv * 16 + lq;
                int koff = kk * 64 + lg * 16;
                int aoff = (row * 128 + koff) ^ ((row & 7) << 4);
                bf16x8 ah = *(const bf16x8*)(Ah + aoff);
                bf16x8 al = *(const bf16x8*)(Al + aoff);
#pragma unroll
                for (int j = 0; j < 8; ++j) {
                    int ir   = j * 16 + lq;
                    int woff = (ir * 128 + koff) ^ ((ir & 7) << 4);
                    bf16x8 bh = *(const bf16x8*)(Wh + woff);
                    acc[pj][j] = MFMA16(ah, bh, acc[pj][j]);
                    if (split) {
                        bf16x8 bl = *(const bf16x8*)(Wl + woff);
                        acc[pj][j] = MFMA16(ah, bl, acc[pj][j]);
                        acc[pj][j] = MFMA16(al, bh, acc[pj][j]);
                    }
                }
            }
        }
    }

    // ---- epilogue: theta (QSCALE) and phi, std layout hi/lo
#pragma unroll
    for (int j = 0; j < 8; ++j) {
        int i = j * 16 + lq;
        float bvt = bt[i];
        float bvp = bp[i];
#pragma unroll
        for (int r = 0; r < 4; ++r) {
            int q = n0 + wv * 16 + lg * 4 + r;
            size_t off = ((size_t)b * NN + q) * NCI + i;
            float vt2 = (acc[0][j][r] + bvt) * QSCALE;
            bf16 th = (bf16)vt2;
            qh[off] = th; ql[off] = (bf16)(vt2 - (float)th);
            float vp2 = acc[1][j][r] + bvp;
            bf16 phh = (bf16)vp2;
            kh[off] = phh; kl[off] = (bf16)(vp2 - (float)phh);
        }
    }

    // ---- epilogue: g -> transpose in LDS -> fragment-major vv
    __syncthreads();
    char* T = lds;   // [128 i][64 n] bf16, swizzled (16 KB, reuses Ah/Al)
#pragma unroll
    for (int j = 0; j < 8; ++j) {
        int i = j * 16 + lq;
        float bv2 = bg[i];
#pragma unroll
        for (int r = 0; r < 4; ++r) {
            int nl = wv * 16 + lg * 4 + r;
            int off = (i * 128 + nl * 2) ^ ((i & 7) << 4);
            *(bf16*)(T + off) = (bf16)(acc[2][j][r] + bv2);
        }
    }
    __syncthreads();
#pragma unroll
    for (int p = 0; p < 4; ++p) {
        int i  = p * 32 + (tid >> 3);   // d channel 0..127
        int sl = tid & 7;               // m-octet 0..7
        i32x4 tv = *(const i32x4*)(T + ((i * 128 + sl * 16) ^ ((i & 7) << 4)));
        size_t off = (size_t)b * PBATCH
                   + (size_t)((((nt * 8 + (i >> 4)) * 2 + (sl >> 2)) * 64
                               + (sl & 3) * 16 + (i & 15)) * 8);
        *(i32x4*)(vv + off) = tv;
    }
}

// ---------------------------------------------------------------------------
// Kernel 2: flash attention, BK=64. 512 blocks x 256 thr (2 blocks/CU,
// 8 waves/CU), 4 waves x 32 q (128 q/block), KV-split x2, 32 iterations.
// K double-buffered LDS (64 KB) + reg prefetch, 1 barrier/iter; V
// fragment-major direct from L2, issued AFTER QK^T (R9-proven placement).
// LDS exactly 80 KB -> two blocks fill the 160 KB CU budget.
// ---------------------------------------------------------------------------
__global__ __launch_bounds__(256, 2) void k_attn_sp(
    const bf16* __restrict__ qh, const bf16* __restrict__ ql,
    const bf16* __restrict__ kh, const bf16* __restrict__ kl,
    const bf16* __restrict__ vf,
    bf16* __restrict__ p0, bf16* __restrict__ p1, float* __restrict__ ml)
{
    const int bid = blockIdx.x;       // 0..511
    const int b   = bid & 7;          // batch == XCD (L2 colocation)
    const int rs  = bid >> 3;         // 0..63
    const int qt  = rs & 31;          // 0..31 (128-q tiles)
    const int h   = rs >> 5;          // 0..1  (KV half)
    const int tid = threadIdx.x;      // 0..255
    const int wv  = tid >> 6;         // 0..3
    const int ln  = tid & 63;
    const int lg  = ln >> 4;          // 0..3
    const int lq  = ln & 15;
    const int n0  = qt * 128;
    const int mb0 = h * 2048;
    bf16* ph = h ? p1 : p0;

    // LDS: Kbuf0 32K (KH 16K + KL 16K) | Kbuf1 32K | P 4x4K -> 80 KB
    __shared__ __attribute__((aligned(16))) char lds[81920];
    char* P = lds + 65536 + wv * 4096;   // per-wave [32 q][64 m] bf16, swizzled

    const int smm = tid >> 4;   // staging row within 16-row group (0..15)
    const int ssl = tid & 15;   // staging 16B unit within 256B row

    // ---- Q fragments (2 q-subtiles x 4 k-chunks), hi/lo, loop-invariant
    bf16x8 qhf[2][4], qlf[2][4];
#pragma unroll
    for (int q2 = 0; q2 < 2; ++q2) {
        int qrow = n0 + wv * 32 + q2 * 16 + lq;
        const bf16* bh = qh + ((size_t)b * NN + qrow) * NCI;
        const bf16* bl = ql + ((size_t)b * NN + qrow) * NCI;
#pragma unroll
        for (int kk = 0; kk < 4; ++kk) {
            qhf[q2][kk] = *(const bf16x8*)(bh + kk * 32 + lg * 8);
            qlf[q2][kk] = *(const bf16x8*)(bl + kk * 32 + lg * 8);
        }
    }

    f32x4 o[2][8];
#pragma unroll
    for (int q2 = 0; q2 < 2; ++q2)
#pragma unroll
        for (int j = 0; j < 8; ++j) o[q2][j] = f32x4{0.f, 0.f, 0.f, 0.f};
    float mrun[2] = {-1e30f, -1e30f};
    float lrun[2] = {0.f, 0.f};

    // V fragment-major base: + lane*16B (coalesced)
    const bf16* vb = vf + (size_t)b * PBATCH + (size_t)ln * 8;

    // ---- prologue: stage K tile 0 (64 m) into buf0
    {
#pragma unroll
        for (int p = 0; p < 4; ++p) {
            int mm = p * 16 + smm;
            size_t g = ((size_t)b * NN + mb0 + mm) * NCI + ssl * 8;
            i32x4 hv = *(const i32x4*)(kh + g);
            i32x4 lv = *(const i32x4*)(kl + g);
            int off = (mm * 256 + ssl * 16) ^ ((mm & 7) << 4);
            *(i32x4*)(lds + off) = hv;
            *(i32x4*)(lds + 16384 + off) = lv;
        }
    }
    __syncthreads();

    for (int t = 0; t < 32; ++t) {
        const int cur = t & 1;
        char* KHc = lds + cur * 32768;
        char* KLc = KHc + 16384;
        char* KHn = lds + (cur ^ 1) * 32768;
        char* KLn = KHn + 16384;
        const bool pre = (t < 31);

        // ---- issue K[t+1] prefetch loads (hide under QK^T)
        i32x4 rkh[4], rkl[4];
        if (pre) {
#pragma unroll
            for (int p = 0; p < 4; ++p) {
                size_t g = ((size_t)b * NN + mb0 + (t + 1) * 64 + p * 16 + smm) * NCI + ssl * 8;
                rkh[p] = *(const i32x4*)(kh + g);
                rkl[p] = *(const i32x4*)(kl + g);
            }
        }
        __builtin_amdgcn_sched_barrier(0);

        // ---- swapped QK^T: S^T[64 m][32 q], A=K (LDS), B=Q (regs), 3-MFMA
        f32x4 s[4][2];
        __builtin_amdgcn_s_setprio(1);
#pragma unroll
        for (int jm = 0; jm < 4; ++jm) {
            s[jm][0] = f32x4{0.f, 0.f, 0.f, 0.f};
            s[jm][1] = f32x4{0.f, 0.f, 0.f, 0.f};
            const int mrow = jm * 16 + lq;
            const int sw = (mrow & 7) << 4;
#pragma unroll
            for (int kk = 0; kk < 4; ++kk) {
                int aoff = (mrow * 256 + kk * 64 + lg * 16) ^ sw;
                bf16x8 ah = *(const bf16x8*)(KHc + aoff);
                bf16x8 al = *(const bf16x8*)(KLc + aoff);
                s[jm][0] = MFMA16(ah, qhf[0][kk], s[jm][0]);
                s[jm][1] = MFMA16(ah, qhf[1][kk], s[jm][1]);
                s[jm][0] = MFMA16(al, qhf[0][kk], s[jm][0]);
                s[jm][1] = MFMA16(al, qhf[1][kk], s[jm][1]);
                s[jm][0] = MFMA16(ah, qlf[0][kk], s[jm][0]);
                s[jm][1] = MFMA16(ah, qlf[1][kk], s[jm][1]);
            }
        }
        __builtin_amdgcn_s_setprio(0);

        // ---- issue V[t] fragment loads (latency hides under softmax)
        bf16x8 bv[8][2];
        {
            const bf16* vp = vb + (size_t)(h * 32 + t) * 8192;
#pragma unroll
            for (int j = 0; j < 8; ++j) {
                bv[j][0] = *(const bf16x8*)(vp + (j * 2 + 0) * 512);
                bv[j][1] = *(const bf16x8*)(vp + (j * 2 + 1) * 512);
            }
        }
        __builtin_amdgcn_sched_barrier(0);

        // ---- write K[t+1] into the alternate buffer (reads of it done at
        //      the barrier that ended iteration t-1)
        if (pre) {
#pragma unroll
            for (int p = 0; p < 4; ++p) {
                int mm = p * 16 + smm;
                int off = (mm * 256 + ssl * 16) ^ ((mm & 7) << 4);
                *(i32x4*)(KHn + off) = rkh[p];
                *(i32x4*)(KLn + off) = rkl[p];
            }
        }

        // ---- online softmax (exp2 domain). Lane owns columns q2*16+lq.
        float tm[2];
        tm[0] = s[0][0][0];
        tm[1] = s[0][1][0];
#pragma unroll
        for (int jm = 0; jm < 4; ++jm)
#pragma unroll
            for (int r = 0; r < 4; ++r) {
                tm[0] = fmaxf(tm[0], s[jm][0][r]);
                tm[1] = fmaxf(tm[1], s[jm][1][r]);
            }
#pragma unroll
        for (int q2 = 0; q2 < 2; ++q2) {
            tm[q2] = fmaxf(tm[q2], __shfl_xor(tm[q2], 16));
            tm[q2] = fmaxf(tm[q2], __shfl_xor(tm[q2], 32));
        }

        // defer-max: rescale only when running max grows by > 8 (log2 units)
        bool grow = (tm[0] > mrun[0] + 8.f) || (tm[1] > mrun[1] + 8.f);
        if (__any(grow)) {
            float alpha[2];
#pragma unroll
            for (int q2 = 0; q2 < 2; ++q2) {
                float mnew = fmaxf(mrun[q2], tm[q2]);
                alpha[q2] = exp2f(mrun[q2] - mnew);
                mrun[q2] = mnew;
                lrun[q2] *= alpha[q2];
            }
            float av0[4], av1[4];
#pragma unroll
            for (int r = 0; r < 4; ++r) {
                av0[r] = __shfl(alpha[0], lg * 4 + r);
                av1[r] = __shfl(alpha[1], lg * 4 + r);
            }
#pragma unroll
            for (int j = 0; j < 8; ++j)
#pragma unroll
                for (int r = 0; r < 4; ++r) {
                    o[0][j][r] *= av0[r];
                    o[1][j][r] *= av1[r];
                }
        }

        // ---- P = exp2(S - m), packed bf16x4 writes to per-wave LDS
        float psum[2] = {0.f, 0.f};
#pragma unroll
        for (int jm = 0; jm < 4; ++jm)
#pragma unroll
            for (int q2 = 0; q2 < 2; ++q2) {
                bf16x4 pk;
#pragma unroll
                for (int r = 0; r < 4; ++r) {
                    float e2 = exp2f(s[jm][q2][r] - mrun[q2]);
                    psum[q2] += e2;
                    pk[r] = (bf16)e2;
                }
                int row = q2 * 16 + lq;
                int off = (row * 128 + (jm * 16 + lg * 4) * 2) ^ ((row & 7) << 4);
                *(bf16x4*)(P + off) = pk;
            }
#pragma unroll
        for (int q2 = 0; q2 < 2; ++q2) {
            psum[q2] += __shfl_xor(psum[q2], 16);
            psum[q2] += __shfl_xor(psum[q2], 32);
            lrun[q2] += psum[q2];
        }

        // ---- PV: O[q][d] += P[q][m] * V[m][d]; A=P (LDS), B=V (regs, L2)
        bf16x8 pa[2][2];
#pragma unroll
        for (int q2 = 0; q2 < 2; ++q2)
#pragma unroll
            for (int tt = 0; tt < 2; ++tt) {
                int row = q2 * 16 + lq;
                pa[q2][tt] = *(const bf16x8*)(P + ((row * 128 + tt * 64 + lg * 16) ^ ((row & 7) << 4)));
            }
        __builtin_amdgcn_s_setprio(1);
#pragma unroll
        for (int j = 0; j < 8; ++j) {
            o[0][j] = MFMA16(pa[0][0], bv[j][0], o[0][j]);
            o[1][j] = MFMA16(pa[1][0], bv[j][0], o[1][j]);
            o[0][j] = MFMA16(pa[0][1], bv[j][1], o[0][j]);
            o[1][j] = MFMA16(pa[1][1], bv[j][1], o[1][j]);
        }
        __builtin_amdgcn_s_setprio(0);

        __syncthreads();   // K[t+1] visible; all reads of buf[cur] complete
    }

    // ---- epilogue: partial y_h = O / l (bf16), plus (m, l) per row
    float rl0[4], rl1[4];
#pragma unroll
    for (int r = 0; r < 4; ++r) {
        rl0[r] = 1.f / __shfl(lrun[0], lg * 4 + r);
        rl1[r] = 1.f / __shfl(lrun[1], lg * 4 + r);
    }
#pragma unroll
    for (int j = 0; j < 8; ++j) {
        int d = j * 16 + lq;
#pragma unroll
        for (int r = 0; r < 4; ++r) {
            int q0 = n0 + wv * 32 + lg * 4 + r;
            ph[((size_t)b * NN + q0) * NCI + d]      = (bf16)(o[0][j][r] * rl0[r]);
            ph[((size_t)b * NN + q0 + 16) * NCI + d] = (bf16)(o[1][j][r] * rl1[r]);
        }
    }
    if (lg == 0) {
#pragma unroll
        for (int q2 = 0; q2 < 2; ++q2) {
            int row = n0 + wv * 32 + q2 * 16 + lq;
            size_t base = ((size_t)b * NN + row) * 4 + h * 2;
            ml[base]     = mrun[q2];   // log2 domain
            ml[base + 1] = lrun[q2];
        }
    }
}

// ---------------------------------------------------------------------------
// Kernel 3: fused combine + output GEMM.
// y[n,i] = w0*p0 + w1*p1 (KV-split merge, exp2 domain), staged in LDS;
// out[b,c,n] = x[b,c,n] + sum_i y[n,i]*w_out[c,i] + b_out[c].
// Uses pre-converted bf16 w_out (wob) when available.
// ---------------------------------------------------------------------------
__global__ __launch_bounds__(256) void k_out(
    const bf16* __restrict__ p0, const bf16* __restrict__ p1,
    const float* __restrict__ ml, const float* __restrict__ x,
    const float* __restrict__ w_out, const bf16* __restrict__ wob,
    const float* __restrict__ b_out, float* __restrict__ out)
{
    const int nt  = blockIdx.x;
    const int b   = blockIdx.y;
    const int tid = threadIdx.x;
    const int wv  = tid >> 6;
    const int ln  = tid & 63;
    const int lg  = ln >> 4;
    const int lq  = ln & 15;
    const int n0  = nt * 64;

    __shared__ char Y[16384];   // [64 n][128 i] bf16, swizzled
#pragma unroll
    for (int p = 0; p < 4; ++p) {
        int nn = p * 16 + (tid >> 4);
        int d0 = (tid & 15) * 8;
        size_t row = (size_t)b * NN + n0 + nn;
        f32x4 q = *(const f32x4*)(ml + row * 4);  // m0 l0 m1 l1 (log2 domain)
        float M  = fmaxf(q[0], q[2]);
        float w0 = exp2f(q[0] - M) * q[1];
        float w1 = exp2f(q[2] - M) * q[3];
        float inv = 1.f / (w0 + w1);
        w0 *= inv; w1 *= inv;
        size_t off = row * NCI + d0;
        bf16x8 a = *(const bf16x8*)(p0 + off);
        bf16x8 c = *(const bf16x8*)(p1 + off);
        bf16x8 rr;
#pragma unroll
        for (int e = 0; e < 8; ++e)
            rr[e] = (bf16)(w0 * (float)a[e] + w1 * (float)c[e]);
        *(bf16x8*)(Y + ((nn * 256 + d0 * 2) ^ ((nn & 7) << 4))) = rr;
    }
    __syncthreads();

    bf16x8 af[4];
    {
        int row = wv * 16 + lq;
#pragma unroll
        for (int kk = 0; kk < 4; ++kk) {
            int koff = kk * 64 + lg * 16;
            af[kk] = *(const bf16x8*)(Y + ((row * 256 + koff) ^ ((row & 7) << 4)));
        }
    }

    f32x4 acc[16];
#pragma unroll
    for (int j = 0; j < 16; ++j) acc[j] = f32x4{0.f, 0.f, 0.f, 0.f};

    if (wob != nullptr) {
#pragma unroll
        for (int j = 0; j < 16; ++j) {
            int c = j * 16 + lq;
#pragma unroll
            for (int kk = 0; kk < 4; ++kk) {
                int i0 = kk * 32 + lg * 8;
                bf16x8 bw = *(const bf16x8*)(wob + (size_t)c * NCI + i0);
                acc[j] = MFMA16(af[kk], bw, acc[j]);
            }
        }
    } else {
#pragma unroll
        for (int j = 0; j < 16; ++j) {
            int c = j * 16 + lq;
#pragma unroll
            for (int kk = 0; kk < 4; ++kk) {
                int i0 = kk * 32 + lg * 8;
                f32x4 wa = *(const f32x4*)(w_out + (size_t)c * NCI + i0);
                f32x4 wb = *(const f32x4*)(w_out + (size_t)c * NCI + i0 + 4);
                bf16x8 bw;
#pragma unroll
                for (int e = 0; e < 4; ++e) { bw[e] = (bf16)wa[e]; bw[e + 4] = (bf16)wb[e]; }
                acc[j] = MFMA16(af[kk], bw, acc[j]);
            }
        }
    }

#pragma unroll
    for (int j = 0; j < 16; ++j) {
        int c = j * 16 + lq;
        int nb = n0 + wv * 16 + lg * 4;
        size_t off = ((size_t)b * NC + c) * (size_t)NN + nb;
        f32x4 xv = *(const f32x4*)(x + off);
        float bo = b_out[c];
        f32x4 r;
#pragma unroll
        for (int t = 0; t < 4; ++t) r[t] = acc[j][t] + xv[t] + bo;
        *(f32x4*)(out + off) = r;
    }
}

// ---------------------------------------------------------------------------
extern "C" void kernel_launch(void* const* d_in, const int* in_sizes, int n_in,
                              void* d_out, int out_size, void* d_ws, size_t ws_size,
                              hipStream_t stream)
{
    (void)in_sizes; (void)n_in; (void)out_size;
    const float* x  = (const float*)d_in[0];
    const float* wg = (const float*)d_in[1];
    const float* bg = (const float*)d_in[2];
    const float* wt = (const float*)d_in[3];
    const float* bt = (const float*)d_in[4];
    const float* wp = (const float*)d_in[5];
    const float* bp = (const float*)d_in[6];
    const float* wo = (const float*)d_in[7];
    const float* bo = (const float*)d_in[8];
    float* out = (float*)d_out;

    char* ws = (char*)d_ws;
    bf16* qh = (bf16*)(ws);
    bf16* ql = (bf16*)(ws + NEL * 2);
    bf16* kh = (bf16*)(ws + NEL * 4);    // standard [b][m][d] hi
    bf16* kl = (bf16*)(ws + NEL * 6);    // standard [b][m][d] lo
    bf16* vv = (bf16*)(ws + NEL * 8);    // fragment-major V
    bf16* p0 = (bf16*)(ws + NEL * 10);   // KV-split partials
    bf16* p1 = (bf16*)(ws + NEL * 12);
    float* ml = (float*)(ws + NEL * 14); // ws >= NEL*14 + 512K proven (R4)
    const size_t ml_bytes = (size_t)NB * NN * 4 * sizeof(float);
    // optional pre-converted w_out (bf16, 64 KB) — only if workspace allows
    bf16* wob = nullptr;
    if (ws_size >= NEL * 14 + ml_bytes + (size_t)NC * NCI * sizeof(bf16))
        wob = (bf16*)(ws + NEL * 14 + ml_bytes);

    k_proj3<<<dim3(64, 8), 256, 0, stream>>>(x, wt, bt, wp, bp, wg, bg,
                                             wo, wob, qh, ql, kh, kl, vv);
    k_attn_sp<<<dim3(512), 256, 0, stream>>>(qh, ql, kh, kl, vv, p0, p1, ml);
    k_out<<<dim3(64, 8), 256, 0, stream>>>(p0, p1, ml, x, wo, wob, bo, out);
}

// Round 13
// 235.817 us; speedup vs baseline: 1.5727x; 1.5727x over previous
//
#include <hip/hip_runtime.h>
#include <hip/hip_bf16.h>
#include <stdint.h>
#include <stddef.h>

// ---------------------------------------------------------------------------
// NonLocalBlock2D: B=8, C=256, H=W=64 (N=4096), CI=128
// out = x + Wout * softmax( (theta(x)^T phi(x)) * sqrt(CI) ) * g(x)
// Split-fp32 (bf16 hi+lo, 3-MFMA) upstream of softmax; plain bf16 after.
// theta pre-scaled by sqrt(128)/ln2 -> softmax in exp2 domain.
// k_proj3: three projections fused (x staged once) + w_out pre-convert.
// k_attn_sp: R11-exact — 1024 blocks x 128 thr (4 blocks/CU), 2 waves x
// 32 q, BK=32, KV-split x2; K double-buffered LDS + reg prefetch, 1 barrier
// per iter; V fragment-major from L2 issued after QK^T. (BK=64 spilled:
// R12 FETCH/WRITE tripled from scratch traffic — register ledger > 256.)
// k_out: combine of KV-split partials fused into the output GEMM; uses
// pre-converted bf16 w_out.
// ---------------------------------------------------------------------------

typedef __bf16 bf16;
typedef __attribute__((ext_vector_type(8))) __bf16 bf16x8;
typedef __attribute__((ext_vector_type(4))) __bf16 bf16x4;
typedef __attribute__((ext_vector_type(4))) float  f32x4;
typedef __attribute__((ext_vector_type(4))) int    i32x4;

#define MFMA16(a, b, c) __builtin_amdgcn_mfma_f32_16x16x32_bf16((a), (b), (c), 0, 0, 0)

constexpr int NB  = 8;
constexpr int NC  = 256;
constexpr int NN  = 4096;
constexpr int NCI = 128;
constexpr size_t NEL = (size_t)NB * NN * NCI;
constexpr int PBATCH = NN * NCI;       // elems per batch

// sqrt(128) / ln(2): folded into theta so logits are in log2 units.
#define QSCALE (11.313708498984761f * 1.4426950408889634f)

// V fragment layout (16x16x32 MFMA B-operand):
//  Vf[b][m>>6][j=d>>4][tt=(m&63)>>5][lane][8], lane=((m>>3)&3)*16+(d&15), e=m&7

// ---------------------------------------------------------------------------
// Kernel 1: fused projections. Block (nt, b) computes theta/phi/g for a
// 64-n x 128-i tile. x-tile staged (and fp32-split) ONCE per c0 chunk;
// W staged sequentially per projection in a reused LDS buffer.
// theta -> qh/ql (*QSCALE), phi -> kh/kl, g -> fragment-major vv.
// Also pre-converts w_out fp32->bf16 (64 elems/block side job).
// ---------------------------------------------------------------------------
__global__ __launch_bounds__(256) void k_proj3(
    const float* __restrict__ x,
    const float* __restrict__ wt, const float* __restrict__ bt,
    const float* __restrict__ wp, const float* __restrict__ bp,
    const float* __restrict__ wg, const float* __restrict__ bg,
    const float* __restrict__ wo, bf16* __restrict__ wob,
    bf16* __restrict__ qh, bf16* __restrict__ ql,
    bf16* __restrict__ kh, bf16* __restrict__ kl,
    bf16* __restrict__ vv)
{
    const int nt  = blockIdx.x;      // 0..63
    const int b   = blockIdx.y;      // 0..7
    const int tid = threadIdx.x;
    const int wv  = tid >> 6;
    const int ln  = tid & 63;
    const int lg  = ln >> 4;
    const int lq  = ln & 15;

    // side job: pre-convert w_out (256x128 fp32 -> bf16), 64 elems per block
    if (wob != nullptr && tid < 16) {
        int idx = (b * 64 + nt) * 64 + tid * 4;
        f32x4 w4 = *(const f32x4*)(wo + idx);
        bf16x4 o4;
#pragma unroll
        for (int e = 0; e < 4; ++e) o4[e] = (bf16)w4[e];
        *(bf16x4*)(wob + idx) = o4;
    }

    __shared__ char lds[49152];
    char* Ah = lds;            // [64 n][64 c] bf16 hi, swizzled (8 KB)
    char* Al = lds + 8192;     // lo
    char* Wh = lds + 16384;    // [128 i][64 c] bf16 hi, swizzled (16 KB)
    char* Wl = lds + 32768;    // lo

    f32x4 acc[3][8];
#pragma unroll
    for (int pj = 0; pj < 3; ++pj)
#pragma unroll
        for (int j = 0; j < 8; ++j) acc[pj][j] = f32x4{0.f, 0.f, 0.f, 0.f};

    const int n0 = nt * 64;

    for (int c0 = 0; c0 < NC; c0 += 64) {
        __syncthreads();
        // ---- stage x chunk once: x[b, c0+cc, n0+nn] -> Ah/Al[nn][cc]
#pragma unroll
        for (int p = 0; p < 4; ++p) {
            int cc = p * 16 + (tid >> 4);
            int nn = (tid & 15) * 4;
            f32x4 xv = *(const f32x4*)(x + ((size_t)b * NC + (c0 + cc)) * NN + n0 + nn);
#pragma unroll
            for (int e = 0; e < 4; ++e) {
                float f = xv[e];
                bf16 hh = (bf16)f;
                int row = nn + e;
                int off = (row * 128 + cc * 2) ^ ((row & 7) << 4);
                *(bf16*)(Ah + off) = hh;
                *(bf16*)(Al + off) = (bf16)(f - (float)hh);
            }
        }

        // ---- three projections, sequential W staging
#pragma unroll
        for (int pj = 0; pj < 3; ++pj) {
            const float* W = (pj == 0) ? wt : (pj == 1) ? wp : wg;
            const bool split = (pj != 2);
            if (pj != 0) __syncthreads();   // done reading previous W
#pragma unroll
            for (int p = 0; p < 8; ++p) {
                int i  = p * 16 + (tid >> 4);
                int c4 = (tid & 15) * 4;
                f32x4 w4 = *(const f32x4*)(W + (size_t)i * NC + c0 + c4);
                bf16x4 hv, lv;
#pragma unroll
                for (int e = 0; e < 4; ++e) {
                    bf16 hh = (bf16)w4[e];
                    hv[e] = hh;
                    lv[e] = (bf16)(w4[e] - (float)hh);
                }
                int off = (i * 128 + c4 * 2) ^ ((i & 7) << 4);
                *(bf16x4*)(Wh + off) = hv;
                if (split) *(bf16x4*)(Wl + off) = lv;
            }
            __syncthreads();
#pragma unroll
            for (int kk = 0; kk < 2; ++kk) {
                int row  = wv * 16 + lq;
                int koff = kk * 64 + lg * 16;
                int aoff = (row * 128 + koff) ^ ((row & 7) << 4);
                bf16x8 ah = *(const bf16x8*)(Ah + aoff);
                bf16x8 al = *(const bf16x8*)(Al + aoff);
#pragma unroll
                for (int j = 0; j < 8; ++j) {
                    int ir   = j * 16 + lq;
                    int woff = (ir * 128 + koff) ^ ((ir & 7) << 4);
                    bf16x8 bh = *(const bf16x8*)(Wh + woff);
                    acc[pj][j] = MFMA16(ah, bh, acc[pj][j]);
                    if (split) {
                        bf16x8 bl = *(const bf16x8*)(Wl + woff);
                        acc[pj][j] = MFMA16(ah, bl, acc[pj][j]);
                        acc[pj][j] = MFMA16(al, bh, acc[pj][j]);
                    }
                }
            }
        }
    }

    // ---- epilogue: theta (QSCALE) and phi, std layout hi/lo
#pragma unroll
    for (int j = 0; j < 8; ++j) {
        int i = j * 16 + lq;
        float bvt = bt[i];
        float bvp = bp[i];
#pragma unroll
        for (int r = 0; r < 4; ++r) {
            int q = n0 + wv * 16 + lg * 4 + r;
            size_t off = ((size_t)b * NN + q) * NCI + i;
            float vt2 = (acc[0][j][r] + bvt) * QSCALE;
            bf16 th = (bf16)vt2;
            qh[off] = th; ql[off] = (bf16)(vt2 - (float)th);
            float vp2 = acc[1][j][r] + bvp;
            bf16 phh = (bf16)vp2;
            kh[off] = phh; kl[off] = (bf16)(vp2 - (float)phh);
        }
    }

    // ---- epilogue: g -> transpose in LDS -> fragment-major vv
    __syncthreads();
    char* T = lds;   // [128 i][64 n] bf16, swizzled (16 KB, reuses Ah/Al)
#pragma unroll
    for (int j = 0; j < 8; ++j) {
        int i = j * 16 + lq;
        float bv2 = bg[i];
#pragma unroll
        for (int r = 0; r < 4; ++r) {
            int nl = wv * 16 + lg * 4 + r;
            int off = (i * 128 + nl * 2) ^ ((i & 7) << 4);
            *(bf16*)(T + off) = (bf16)(acc[2][j][r] + bv2);
        }
    }
    __syncthreads();
#pragma unroll
    for (int p = 0; p < 4; ++p) {
        int i  = p * 32 + (tid >> 3);   // d channel 0..127
        int sl = tid & 7;               // m-octet 0..7
        i32x4 tv = *(const i32x4*)(T + ((i * 128 + sl * 16) ^ ((i & 7) << 4)));
        size_t off = (size_t)b * PBATCH
                   + (size_t)((((nt * 8 + (i >> 4)) * 2 + (sl >> 2)) * 64
                               + (sl & 3) * 16 + (i & 15)) * 8);
        *(i32x4*)(vv + off) = tv;
    }
}

// ---------------------------------------------------------------------------
// Kernel 2: flash attention (R11-exact). 1024 blocks x 128 thr (4 blocks/CU),
// 2 waves x 32 q, BK=32, KV-split x2. K double-buffered LDS + reg prefetch
// (1 barrier/iter); V fragment-major direct from L2, issued AFTER QK^T.
// ---------------------------------------------------------------------------
__global__ __launch_bounds__(128, 2) void k_attn_sp(
    const bf16* __restrict__ qh, const bf16* __restrict__ ql,
    const bf16* __restrict__ kh, const bf16* __restrict__ kl,
    const bf16* __restrict__ vf,
    bf16* __restrict__ p0, bf16* __restrict__ p1, float* __restrict__ ml)
{
    const int bid = blockIdx.x;       // 0..1023
    const int b   = bid & 7;          // batch == XCD (L2 colocation)
    const int rs  = bid >> 3;         // 0..127
    const int qt  = rs & 63;          // 0..63
    const int h   = rs >> 6;          // 0..1  (KV half)
    const int tid = threadIdx.x;      // 0..127
    const int wv  = tid >> 6;         // 0..1
    const int ln  = tid & 63;
    const int lg  = ln >> 4;          // 0..3
    const int lq  = ln & 15;
    const int n0  = qt * 64;
    const int mb0 = h * 2048;
    bf16* ph = h ? p1 : p0;

    // LDS: Kbuf0 16K (KH 8K + KL 8K) | Kbuf1 16K | P 2x2K -> 36 KB
    __shared__ __attribute__((aligned(16))) char lds[36864];
    char* P = lds + 32768 + wv * 2048;   // per-wave [32 q][32 m] bf16, swizzled

    const int smm = tid >> 4;   // staging row within 8-row group (0..7)
    const int ssl = tid & 15;   // staging 16B unit within 256B row

    // ---- Q fragments (2 q-subtiles x 4 k-chunks), hi/lo, loop-invariant
    bf16x8 qhf[2][4], qlf[2][4];
#pragma unroll
    for (int q2 = 0; q2 < 2; ++q2) {
        int qrow = n0 + wv * 32 + q2 * 16 + lq;
        const bf16* bh = qh + ((size_t)b * NN + qrow) * NCI;
        const bf16* bl = ql + ((size_t)b * NN + qrow) * NCI;
#pragma unroll
        for (int kk = 0; kk < 4; ++kk) {
            qhf[q2][kk] = *(const bf16x8*)(bh + kk * 32 + lg * 8);
            qlf[q2][kk] = *(const bf16x8*)(bl + kk * 32 + lg * 8);
        }
    }

    f32x4 o[2][8];
#pragma unroll
    for (int q2 = 0; q2 < 2; ++q2)
#pragma unroll
        for (int j = 0; j < 8; ++j) o[q2][j] = f32x4{0.f, 0.f, 0.f, 0.f};
    float mrun[2] = {-1e30f, -1e30f};
    float lrun[2] = {0.f, 0.f};

    // V fragment-major base: + lane*16B (coalesced)
    const bf16* vb = vf + (size_t)b * PBATCH + (size_t)ln * 8;

    // ---- prologue: stage K tile 0 (32 m) into buf0
    {
#pragma unroll
        for (int p = 0; p < 4; ++p) {
            int mm = p * 8 + smm;
            size_t g = ((size_t)b * NN + mb0 + mm) * NCI + ssl * 8;
            i32x4 hv = *(const i32x4*)(kh + g);
            i32x4 lv = *(const i32x4*)(kl + g);
            int off = (mm * 256 + ssl * 16) ^ ((mm & 7) << 4);
            *(i32x4*)(lds + off) = hv;
            *(i32x4*)(lds + 8192 + off) = lv;
        }
    }
    __syncthreads();

    for (int t = 0; t < 64; ++t) {
        const int cur = t & 1;
        char* KHc = lds + cur * 16384;
        char* KLc = KHc + 8192;
        char* KHn = lds + (cur ^ 1) * 16384;
        char* KLn = KHn + 8192;
        const bool pre = (t < 63);

        // ---- issue K[t+1] prefetch loads (hide under QK^T)
        i32x4 rkh[4], rkl[4];
        if (pre) {
#pragma unroll
            for (int p = 0; p < 4; ++p) {
                size_t g = ((size_t)b * NN + mb0 + (t + 1) * 32 + p * 8 + smm) * NCI + ssl * 8;
                rkh[p] = *(const i32x4*)(kh + g);
                rkl[p] = *(const i32x4*)(kl + g);
            }
        }
        __builtin_amdgcn_sched_barrier(0);

        // ---- swapped QK^T: S^T[32 m][32 q], A=K (LDS), B=Q (regs), 3-MFMA
        f32x4 s[2][2];
        __builtin_amdgcn_s_setprio(1);
#pragma unroll
        for (int jm = 0; jm < 2; ++jm) {
            s[jm][0] = f32x4{0.f, 0.f, 0.f, 0.f};
            s[jm][1] = f32x4{0.f, 0.f, 0.f, 0.f};
            const int mrow = jm * 16 + lq;
            const int sw = (mrow & 7) << 4;
#pragma unroll
            for (int kk = 0; kk < 4; ++kk) {
                int aoff = (mrow * 256 + kk * 64 + lg * 16) ^ sw;
                bf16x8 ah = *(const bf16x8*)(KHc + aoff);
                bf16x8 al = *(const bf16x8*)(KLc + aoff);
                s[jm][0] = MFMA16(ah, qhf[0][kk], s[jm][0]);
                s[jm][1] = MFMA16(ah, qhf[1][kk], s[jm][1]);
                s[jm][0] = MFMA16(al, qhf[0][kk], s[jm][0]);
                s[jm][1] = MFMA16(al, qhf[1][kk], s[jm][1]);
                s[jm][0] = MFMA16(ah, qlf[0][kk], s[jm][0]);
                s[jm][1] = MFMA16(ah, qlf[1][kk], s[jm][1]);
            }
        }
        __builtin_amdgcn_s_setprio(0);

        // ---- issue V[t] fragment loads (latency hides under softmax)
        bf16x8 bv[8];
        {
            const bf16* vp = vb + (size_t)(h * 32 + (t >> 1)) * 8192;
#pragma unroll
            for (int j = 0; j < 8; ++j)
                bv[j] = *(const bf16x8*)(vp + (j * 2 + (t & 1)) * 512);
        }
        __builtin_amdgcn_sched_barrier(0);

        // ---- write K[t+1] into the alternate buffer (reads of cur done)
        if (pre) {
#pragma unroll
            for (int p = 0; p < 4; ++p) {
                int mm = p * 8 + smm;
                int off = (mm * 256 + ssl * 16) ^ ((mm & 7) << 4);
                *(i32x4*)(KHn + off) = rkh[p];
                *(i32x4*)(KLn + off) = rkl[p];
            }
        }

        // ---- online softmax (exp2 domain). Lane owns columns q2*16+lq.
        float tm[2];
        tm[0] = s[0][0][0];
        tm[1] = s[0][1][0];
#pragma unroll
        for (int jm = 0; jm < 2; ++jm)
#pragma unroll
            for (int r = 0; r < 4; ++r) {
                tm[0] = fmaxf(tm[0], s[jm][0][r]);
                tm[1] = fmaxf(tm[1], s[jm][1][r]);
            }
#pragma unroll
        for (int q2 = 0; q2 < 2; ++q2) {
            tm[q2] = fmaxf(tm[q2], __shfl_xor(tm[q2], 16));
            tm[q2] = fmaxf(tm[q2], __shfl_xor(tm[q2], 32));
        }

        // defer-max: rescale only when running max grows by > 8 (log2 units)
        bool grow = (tm[0] > mrun[0] + 8.f) || (tm[1] > mrun[1] + 8.f);
        if (__any(grow)) {
            float alpha[2];
#pragma unroll
            for (int q2 = 0; q2 < 2; ++q2) {
                float mnew = fmaxf(mrun[q2], tm[q2]);
                alpha[q2] = exp2f(mrun[q2] - mnew);
                mrun[q2] = mnew;
                lrun[q2] *= alpha[q2];
            }
            float av0[4], av1[4];
#pragma unroll
            for (int r = 0; r < 4; ++r) {
                av0[r] = __shfl(alpha[0], lg * 4 + r);
                av1[r] = __shfl(alpha[1], lg * 4 + r);
            }
#pragma unroll
            for (int j = 0; j < 8; ++j)
#pragma unroll
                for (int r = 0; r < 4; ++r) {
                    o[0][j][r] *= av0[r];
                    o[1][j][r] *= av1[r];
                }
        }

        // ---- P = exp2(S - m), packed bf16x4 writes to per-wave LDS
        float psum[2] = {0.f, 0.f};
#pragma unroll
        for (int jm = 0; jm < 2; ++jm)
#pragma unroll
            for (int q2 = 0; q2 < 2; ++q2) {
                bf16x4 pk;
#pragma unroll
                for (int r = 0; r < 4; ++r) {
                    float e2 = exp2f(s[jm][q2][r] - mrun[q2]);
                    psum[q2] += e2;
                    pk[r] = (bf16)e2;
                }
                int row = q2 * 16 + lq;
                int off = (row * 64 + (jm * 16 + lg * 4) * 2) ^ ((row & 7) << 4);
                *(bf16x4*)(P + off) = pk;
            }
#pragma unroll
        for (int q2 = 0; q2 < 2; ++q2) {
            psum[q2] += __shfl_xor(psum[q2], 16);
            psum[q2] += __shfl_xor(psum[q2], 32);
            lrun[q2] += psum[q2];
        }

        // ---- PV: O[q][d] += P[q][m] * V[m][d]; A=P (LDS), B=V (regs, L2)
        bf16x8 pa[2];
#pragma unroll
        for (int q2 = 0; q2 < 2; ++q2) {
            int row = q2 * 16 + lq;
            pa[q2] = *(const bf16x8*)(P + ((row * 64 + lg * 16) ^ ((row & 7) << 4)));
        }
        __builtin_amdgcn_s_setprio(1);
#pragma unroll
        for (int j = 0; j < 8; ++j) {
            o[0][j] = MFMA16(pa[0], bv[j], o[0][j]);
            o[1][j] = MFMA16(pa[1], bv[j], o[1][j]);
        }
        __builtin_amdgcn_s_setprio(0);

        __syncthreads();   // K[t+1] visible; all reads of buf[cur] complete
    }

    // ---- epilogue: partial y_h = O / l (bf16), plus (m, l) per row
    float rl0[4], rl1[4];
#pragma unroll
    for (int r = 0; r < 4; ++r) {
        rl0[r] = 1.f / __shfl(lrun[0], lg * 4 + r);
        rl1[r] = 1.f / __shfl(lrun[1], lg * 4 + r);
    }
#pragma unroll
    for (int j = 0; j < 8; ++j) {
        int d = j * 16 + lq;
#pragma unroll
        for (int r = 0; r < 4; ++r) {
            int q0 = n0 + wv * 32 + lg * 4 + r;
            ph[((size_t)b * NN + q0) * NCI + d]      = (bf16)(o[0][j][r] * rl0[r]);
            ph[((size_t)b * NN + q0 + 16) * NCI + d] = (bf16)(o[1][j][r] * rl1[r]);
        }
    }
    if (lg == 0) {
#pragma unroll
        for (int q2 = 0; q2 < 2; ++q2) {
            int row = n0 + wv * 32 + q2 * 16 + lq;
            size_t base = ((size_t)b * NN + row) * 4 + h * 2;
            ml[base]     = mrun[q2];   // log2 domain
            ml[base + 1] = lrun[q2];
        }
    }
}

// ---------------------------------------------------------------------------
// Kernel 3: fused combine + output GEMM.
// y[n,i] = w0*p0 + w1*p1 (KV-split merge, exp2 domain), staged in LDS;
// out[b,c,n] = x[b,c,n] + sum_i y[n,i]*w_out[c,i] + b_out[c].
// Uses pre-converted bf16 w_out (wob) when available.
// ---------------------------------------------------------------------------
__global__ __launch_bounds__(256) void k_out(
    const bf16* __restrict__ p0, const bf16* __restrict__ p1,
    const float* __restrict__ ml, const float* __restrict__ x,
    const float* __restrict__ w_out, const bf16* __restrict__ wob,
    const float* __restrict__ b_out, float* __restrict__ out)
{
    const int nt  = blockIdx.x;
    const int b   = blockIdx.y;
    const int tid = threadIdx.x;
    const int wv  = tid >> 6;
    const int ln  = tid & 63;
    const int lg  = ln >> 4;
    const int lq  = ln & 15;
    const int n0  = nt * 64;

    __shared__ char Y[16384];   // [64 n][128 i] bf16, swizzled
#pragma unroll
    for (int p = 0; p < 4; ++p) {
        int nn = p * 16 + (tid >> 4);
        int d0 = (tid & 15) * 8;
        size_t row = (size_t)b * NN + n0 + nn;
        f32x4 q = *(const f32x4*)(ml + row * 4);  // m0 l0 m1 l1 (log2 domain)
        float M  = fmaxf(q[0], q[2]);
        float w0 = exp2f(q[0] - M) * q[1];
        float w1 = exp2f(q[2] - M) * q[3];
        float inv = 1.f / (w0 + w1);
        w0 *= inv; w1 *= inv;
        size_t off = row * NCI + d0;
        bf16x8 a = *(const bf16x8*)(p0 + off);
        bf16x8 c = *(const bf16x8*)(p1 + off);
        bf16x8 rr;
#pragma unroll
        for (int e = 0; e < 8; ++e)
            rr[e] = (bf16)(w0 * (float)a[e] + w1 * (float)c[e]);
        *(bf16x8*)(Y + ((nn * 256 + d0 * 2) ^ ((nn & 7) << 4))) = rr;
    }
    __syncthreads();

    bf16x8 af[4];
    {
        int row = wv * 16 + lq;
#pragma unroll
        for (int kk = 0; kk < 4; ++kk) {
            int koff = kk * 64 + lg * 16;
            af[kk] = *(const bf16x8*)(Y + ((row * 256 + koff) ^ ((row & 7) << 4)));
        }
    }

    f32x4 acc[16];
#pragma unroll
    for (int j = 0; j < 16; ++j) acc[j] = f32x4{0.f, 0.f, 0.f, 0.f};

    if (wob != nullptr) {
#pragma unroll
        for (int j = 0; j < 16; ++j) {
            int c = j * 16 + lq;
#pragma unroll
            for (int kk = 0; kk < 4; ++kk) {
                int i0 = kk * 32 + lg * 8;
                bf16x8 bw = *(const bf16x8*)(wob + (size_t)c * NCI + i0);
                acc[j] = MFMA16(af[kk], bw, acc[j]);
            }
        }
    } else {
#pragma unroll
        for (int j = 0; j < 16; ++j) {
            int c = j * 16 + lq;
#pragma unroll
            for (int kk = 0; kk < 4; ++kk) {
                int i0 = kk * 32 + lg * 8;
                f32x4 wa = *(const f32x4*)(w_out + (size_t)c * NCI + i0);
                f32x4 wb = *(const f32x4*)(w_out + (size_t)c * NCI + i0 + 4);
                bf16x8 bw;
#pragma unroll
                for (int e = 0; e < 4; ++e) { bw[e] = (bf16)wa[e]; bw[e + 4] = (bf16)wb[e]; }
                acc[j] = MFMA16(af[kk], bw, acc[j]);
            }
        }
    }

#pragma unroll
    for (int j = 0; j < 16; ++j) {
        int c = j * 16 + lq;
        int nb = n0 + wv * 16 + lg * 4;
        size_t off = ((size_t)b * NC + c) * (size_t)NN + nb;
        f32x4 xv = *(const f32x4*)(x + off);
        float bo = b_out[c];
        f32x4 r;
#pragma unroll
        for (int t = 0; t < 4; ++t) r[t] = acc[j][t] + xv[t] + bo;
        *(f32x4*)(out + off) = r;
    }
}

// ---------------------------------------------------------------------------
extern "C" void kernel_launch(void* const* d_in, const int* in_sizes, int n_in,
                              void* d_out, int out_size, void* d_ws, size_t ws_size,
                              hipStream_t stream)
{
    (void)in_sizes; (void)n_in; (void)out_size;
    const float* x  = (const float*)d_in[0];
    const float* wg = (const float*)d_in[1];
    const float* bg = (const float*)d_in[2];
    const float* wt = (const float*)d_in[3];
    const float* bt = (const float*)d_in[4];
    const float* wp = (const float*)d_in[5];
    const float* bp = (const float*)d_in[6];
    const float* wo = (const float*)d_in[7];
    const float* bo = (const float*)d_in[8];
    float* out = (float*)d_out;

    char* ws = (char*)d_ws;
    bf16* qh = (bf16*)(ws);
    bf16* ql = (bf16*)(ws + NEL * 2);
    bf16* kh = (bf16*)(ws + NEL * 4);    // standard [b][m][d] hi
    bf16* kl = (bf16*)(ws + NEL * 6);    // standard [b][m][d] lo
    bf16* vv = (bf16*)(ws + NEL * 8);    // fragment-major V
    bf16* p0 = (bf16*)(ws + NEL * 10);   // KV-split partials
    bf16* p1 = (bf16*)(ws + NEL * 12);
    float* ml = (float*)(ws + NEL * 14); // ws >= NEL*14 + 512K proven (R4)
    const size_t ml_bytes = (size_t)NB * NN * 4 * sizeof(float);
    // optional pre-converted w_out (bf16, 64 KB) — only if workspace allows
    bf16* wob = nullptr;
    if (ws_size >= NEL * 14 + ml_bytes + (size_t)NC * NCI * sizeof(bf16))
        wob = (bf16*)(ws + NEL * 14 + ml_bytes);

    k_proj3<<<dim3(64, 8), 256, 0, stream>>>(x, wt, bt, wp, bp, wg, bg,
                                             wo, wob, qh, ql, kh, kl, vv);
    k_attn_sp<<<dim3(1024), 128, 0, stream>>>(qh, ql, kh, kl, vv, p0, p1, ml);
    k_out<<<dim3(64, 8), 256, 0, stream>>>(p0, p1, ml, x, wo, wob, bo, out);
}